// Round 8
// baseline (1398.004 us; speedup 1.0000x reference)
//
#include <hip/hip_runtime.h>

// LSTMBaseline: B=2048, T=512, H=128, 4H=512, FF=64, OUT=2 ; fp32 in/out.
// R8 = R7 + forced AGPR placement for weight fragments.
// 256 blocks x 512 threads (8 waves). Pipelined layers, 2 barriers/step:
// MM = { MM0(it), MM1(it-1) }, cell = { cell0(it), cell1(it-1) }.
// Weight frags (192 regs/lane) are laundered into AGPRs via "+a" inline asm
// so the arch-VGPR working set (~40 regs) allocates with ZERO scratch spill;
// previous rounds spilled ~1 reg/wave/step whose vmcnt drain poisoned every
// barrier (~1000 cy/step). gfx950 MFMA reads B operands from AGPR directly.

#define TT 512
#define HH 128
#define GG 512
#define FFD 64
#define BB 8
#define NT 512   // threads per block
#define HP 136   // padded LDS row stride (ushort), 16B-aligned rows

typedef __attribute__((ext_vector_type(8))) short short8;
typedef __attribute__((ext_vector_type(4))) float f32x4;

__device__ __forceinline__ unsigned short f2b(float f) {
    unsigned int i = __builtin_bit_cast(unsigned int, f);
    i += 0x7FFFu + ((i >> 16) & 1u);   // RNE
    return (unsigned short)(i >> 16);
}
__device__ __forceinline__ float b2f(unsigned short u) {
    return __builtin_bit_cast(float, ((unsigned int)u) << 16);
}
__device__ __forceinline__ float fast_rcp(float x) {
#if __has_builtin(__builtin_amdgcn_rcpf)
    return __builtin_amdgcn_rcpf(x);
#else
    return 1.0f / x;
#endif
}
__device__ __forceinline__ float sigm(float x) {
    return fast_rcp(1.0f + exp2f(-1.4426950408889634f * x));
}
__device__ __forceinline__ float tanh_f(float x) {
    return 1.0f - 2.0f * fast_rcp(1.0f + exp2f(2.8853900817779268f * x));
}
// 8 consecutive fp32 -> bf16 short8 fragment
__device__ __forceinline__ short8 ldfrag(const float* p, unsigned idx) {
    const float4* q = reinterpret_cast<const float4*>(p + idx);
    float4 a = q[0], b = q[1];
    short8 s;
    s[0] = (short)f2b(a.x); s[1] = (short)f2b(a.y);
    s[2] = (short)f2b(a.z); s[3] = (short)f2b(a.w);
    s[4] = (short)f2b(b.x); s[5] = (short)f2b(b.y);
    s[6] = (short)f2b(b.z); s[7] = (short)f2b(b.w);
    return s;
}

__global__ __launch_bounds__(NT, 1) void lstm2_fused(
    const float* __restrict__ hr,
    const float* __restrict__ glu,
    const float* __restrict__ wih0,
    const float* __restrict__ whh0,
    const float* __restrict__ bih0,
    const float* __restrict__ bhh0,
    const float* __restrict__ wih1,
    const float* __restrict__ whh1,
    const float* __restrict__ bih1,
    const float* __restrict__ bhh1,
    const float* __restrict__ w1,
    const float* __restrict__ b1,
    const float* __restrict__ w2,
    const float* __restrict__ b2,
    float* __restrict__ out)
{
    __shared__ __align__(16) unsigned short h0s[16][HP];   // bf16; rows 8..15 stay 0
    __shared__ __align__(16) unsigned short h1s[16][HP];
    __shared__ float gates0[BB][GG];                       // layer-0 pre-acts (raw MM)
    __shared__ float gates1[BB][GG];                       // layer-1 pre-acts (raw MM)
    __shared__ float hrs[BB][TT];
    __shared__ float glus[BB][TT];
    __shared__ float bias0s[GG];   // bih0+bhh0
    __shared__ float bias1s[GG];   // bih1+bhh1
    __shared__ float wih0a[GG];    // wih0[:,0]
    __shared__ float wih0b[GG];    // wih0[:,1]
    __shared__ float hid[BB][FFD];

    const int tid  = threadIdx.x;
    const int lane = tid & 63;
    const int wv   = tid >> 6;        // 0..7
    const int nrow = lane & 15;       // MFMA m (A) / n (B) index
    const int kg   = lane >> 4;       // MFMA k-group 0..3
    const int b0   = blockIdx.x * BB;

    // ---- init LDS ----
    {
        unsigned short* p0 = &h0s[0][0];
        unsigned short* p1 = &h1s[0][0];
        for (int i = tid; i < 16 * HP; i += NT) { p0[i] = 0; p1[i] = 0; }
        for (int g = tid; g < GG; g += NT) {
            bias0s[g] = bih0[g] + bhh0[g];
            bias1s[g] = bih1[g] + bhh1[g];
            wih0a[g]  = wih0[2 * g];
            wih0b[g]  = wih0[2 * g + 1];
        }
        for (int i = tid; i < BB * TT; i += NT) {   // coalesced over t
            int row = i >> 9;
            int t   = i & (TT - 1);
            unsigned gi = (unsigned)(b0 + row) * TT + t;
            hrs[row][t]  = hr[gi];
            glus[row][t] = glu[gi];
        }
    }

    // ---- weight fragments (bf16): wave w owns gate cols [64w, 64w+64) ----
    // B-frag 16x16x32: lane(n=lane&15, q=lane>>4) holds B[k=32kt+8q+j][n] = W[gatecol][k]
    const int nb = wv * 64;
    short8 W0f[4][4];   // w_hh0, K=128             -> 64 regs
    short8 W1f[4][8];   // [w_ih1 ; w_hh1], K=256   -> 128 regs
#pragma unroll
    for (int nt = 0; nt < 4; nt++) {
        unsigned gc = (unsigned)(nb + nt * 16 + nrow);
#pragma unroll
        for (int kt = 0; kt < 4; kt++) {
            unsigned off = gc * HH + kt * 32 + kg * 8;
            W0f[nt][kt]     = ldfrag(whh0, off);
            W1f[nt][kt]     = ldfrag(wih1, off);
            W1f[nt][kt + 4] = ldfrag(whh1, off);
        }
    }
    // Force the loop-invariant weight frags into AGPRs (one-time
    // v_accvgpr_write burst); MFMA reads B from AGPR natively on gfx950.
    // Frees the arch-VGPR file for the working set -> no scratch spill.
#pragma unroll
    for (int nt = 0; nt < 4; nt++) {
#pragma unroll
        for (int kt = 0; kt < 4; kt++) { asm volatile("" : "+a"(W0f[nt][kt])); }
#pragma unroll
        for (int kt = 0; kt < 8; kt++) { asm volatile("" : "+a"(W1f[nt][kt])); }
    }

    // ---- per-thread cell unit (2 reps of (r,j)) ----
    const int j  = tid & 127;         // hidden/gate column
    const int rb = tid >> 7;          // 0..3 (wave-uniform)
    float c0r[2] = {0.f, 0.f};
    float c1r[2] = {0.f, 0.f};
    __syncthreads();

    // ---- pipelined recurrence: it in [0, TT] ----
    for (int it = 0; it <= TT; it++) {
        // ===== MM phase =====
        if (it < TT) {
            // MM0(it): gates0 = h0(it-1) @ w_hh0^T
            f32x4 acc[4];
#pragma unroll
            for (int nt = 0; nt < 4; nt++) { f32x4 z = {0.f, 0.f, 0.f, 0.f}; acc[nt] = z; }
#pragma unroll
            for (int kt = 0; kt < 4; kt++) {
                short8 a = *reinterpret_cast<const short8*>(&h0s[nrow][kt * 32 + kg * 8]);
#pragma unroll
                for (int nt = 0; nt < 4; nt++)
                    acc[nt] = __builtin_amdgcn_mfma_f32_16x16x32_bf16(a, W0f[nt][kt], acc[nt], 0, 0, 0);
            }
            if (kg < 2) {   // C/D: col=lane&15, row=4*kg+r ; batch rows 0..7 valid
#pragma unroll
                for (int nt = 0; nt < 4; nt++) {
                    int col = nb + nt * 16 + nrow;
#pragma unroll
                    for (int r = 0; r < 4; r++)
                        gates0[kg * 4 + r][col] = acc[nt][r];
                }
            }
        }
        if (it > 0) {
            // MM1(it-1): gates1 = [h0(it-1), h1(it-2)] @ [w_ih1; w_hh1]^T
            f32x4 acc[4];
#pragma unroll
            for (int nt = 0; nt < 4; nt++) { f32x4 z = {0.f, 0.f, 0.f, 0.f}; acc[nt] = z; }
#pragma unroll
            for (int kt = 0; kt < 8; kt++) {
                short8 a = (kt < 4)
                    ? *reinterpret_cast<const short8*>(&h0s[nrow][kt * 32 + kg * 8])
                    : *reinterpret_cast<const short8*>(&h1s[nrow][(kt - 4) * 32 + kg * 8]);
#pragma unroll
                for (int nt = 0; nt < 4; nt++)
                    acc[nt] = __builtin_amdgcn_mfma_f32_16x16x32_bf16(a, W1f[nt][kt], acc[nt], 0, 0, 0);
            }
            if (kg < 2) {
#pragma unroll
                for (int nt = 0; nt < 4; nt++) {
                    int col = nb + nt * 16 + nrow;
#pragma unroll
                    for (int r = 0; r < 4; r++)
                        gates1[kg * 4 + r][col] = acc[nt][r];
                }
            }
        }
        __syncthreads();

        // ===== cell phase (2 units per thread) =====
        if (it < TT) {
#pragma unroll
            for (int rep = 0; rep < 2; rep++) {
                int r = rb + rep * 4;           // wave-uniform
                float xh = hrs[r][it];
                float xg = glus[r][it];
                float pi = gates0[r][j]       + bias0s[j]       + xh * wih0a[j]       + xg * wih0b[j];
                float pf = gates0[r][j + 128] + bias0s[j + 128] + xh * wih0a[j + 128] + xg * wih0b[j + 128];
                float pg = gates0[r][j + 256] + bias0s[j + 256] + xh * wih0a[j + 256] + xg * wih0b[j + 256];
                float po = gates0[r][j + 384] + bias0s[j + 384] + xh * wih0a[j + 384] + xg * wih0b[j + 384];
                float ig = sigm(pi), fg = sigm(pf), gg = tanh_f(pg), og = sigm(po);
                float c = fg * c0r[rep] + ig * gg;
                c0r[rep] = c;
                h0s[r][j] = f2b(og * tanh_f(c));
            }
        }
        if (it > 0) {
#pragma unroll
            for (int rep = 0; rep < 2; rep++) {
                int r = rb + rep * 4;
                float pi = gates1[r][j]       + bias1s[j];
                float pf = gates1[r][j + 128] + bias1s[j + 128];
                float pg = gates1[r][j + 256] + bias1s[j + 256];
                float po = gates1[r][j + 384] + bias1s[j + 384];
                float ig = sigm(pi), fg = sigm(pf), gg = tanh_f(pg), og = sigm(po);
                float c = fg * c1r[rep] + ig * gg;
                c1r[rep] = c;
                h1s[r][j] = f2b(og * tanh_f(c));
            }
        }
        __syncthreads();
    }

    // ---- head: hidden = relu(h1 @ w1^T + b1); out = hidden @ w2^T + b2 ----
    {
        int r  = tid >> 6;      // 0..7
        int ff = tid & 63;
        float a2 = 0.f;
        for (int k = 0; k < HH; k++)
            a2 += b2f(h1s[r][k]) * w1[(unsigned)ff * HH + k];
        hid[r][ff] = fmaxf(a2 + b1[ff], 0.f);
    }
    __syncthreads();
    if (tid < 16) {
        int r = tid >> 1;
        int o = tid & 1;
        float a2 = b2[o];
        for (int k = 0; k < FFD; k++)
            a2 += hid[r][k] * w2[(unsigned)o * FFD + k];
        out[(b0 + r) * 2 + o] = a2;    // fp32 output
    }
}

extern "C" void kernel_launch(void* const* d_in, const int* in_sizes, int n_in,
                              void* d_out, int out_size, void* d_ws, size_t ws_size,
                              hipStream_t stream) {
    const float* hr   = (const float*)d_in[0];
    const float* glu  = (const float*)d_in[1];
    const float* wih0 = (const float*)d_in[2];
    const float* whh0 = (const float*)d_in[3];
    const float* bih0 = (const float*)d_in[4];
    const float* bhh0 = (const float*)d_in[5];
    const float* wih1 = (const float*)d_in[6];
    const float* whh1 = (const float*)d_in[7];
    const float* bih1 = (const float*)d_in[8];
    const float* bhh1 = (const float*)d_in[9];
    const float* w1   = (const float*)d_in[10];
    const float* b1   = (const float*)d_in[11];
    const float* w2   = (const float*)d_in[12];
    const float* b2   = (const float*)d_in[13];
    float* out = (float*)d_out;

    lstm2_fused<<<dim3(2048 / BB), dim3(NT), 0, stream>>>(
        hr, glu, wih0, whh0, bih0, bhh0, wih1, whh1, bih1, bhh1,
        w1, b1, w2, b2, out);
}

// Round 9
// 1166.430 us; speedup vs baseline: 1.1985x; 1.1985x over previous
//
#include <hip/hip_runtime.h>

// LSTMBaseline: B=2048, T=512, H=128, 4H=512, FF=64, OUT=2 ; fp32 in/out.
// R9: (1) native v_exp_f32 via __builtin_amdgcn_exp2f (R2..R8 silently used
// OCML exp2f — ~15 inst each, the hidden VALU hog). (2) wave w owns gate cols
// {128g+16w+0..15}, g=0..3 -> MFMA output holds all 4 gates for its 16 cols
// -> gates handoff is intra-wave via per-wave LDS buffer (no barrier).
// (3) h0/h1 double-buffered -> ONE __syncthreads per timestep (512 total).
// (4) A-frags shared MM0/MM1; acc regs reused; cell consts in registers.
// Weights stay as bf16 B-frags laundered into AGPRs (R8: kills scratch spill).

#define TT 512
#define HH 128
#define FFD 64
#define BB 8
#define NT 512   // threads per block = 8 waves
#define HP 136   // padded LDS row stride (ushort); 272B = 16B-aligned rows

typedef __attribute__((ext_vector_type(8))) short short8;
typedef __attribute__((ext_vector_type(4))) float f32x4;

__device__ __forceinline__ unsigned short f2b(float f) {
    unsigned int i = __builtin_bit_cast(unsigned int, f);
    i += 0x7FFFu + ((i >> 16) & 1u);   // RNE
    return (unsigned short)(i >> 16);
}
__device__ __forceinline__ float b2f(unsigned short u) {
    return __builtin_bit_cast(float, ((unsigned int)u) << 16);
}
__device__ __forceinline__ float fexp2(float x) {
#if __has_builtin(__builtin_amdgcn_exp2f)
    return __builtin_amdgcn_exp2f(x);     // v_exp_f32
#else
    return exp2f(x);
#endif
}
__device__ __forceinline__ float frcp(float x) {
#if __has_builtin(__builtin_amdgcn_rcpf)
    return __builtin_amdgcn_rcpf(x);      // v_rcp_f32
#else
    return 1.0f / x;
#endif
}
__device__ __forceinline__ float sigm(float x) {
    return frcp(1.0f + fexp2(-1.4426950408889634f * x));
}
__device__ __forceinline__ float tanh_f(float x) {
    return 1.0f - 2.0f * frcp(1.0f + fexp2(2.8853900817779268f * x));
}
// 8 consecutive fp32 -> bf16 short8 fragment
__device__ __forceinline__ short8 ldfrag(const float* p, unsigned idx) {
    const float4* q = reinterpret_cast<const float4*>(p + idx);
    float4 a = q[0], b = q[1];
    short8 s;
    s[0] = (short)f2b(a.x); s[1] = (short)f2b(a.y);
    s[2] = (short)f2b(a.z); s[3] = (short)f2b(a.w);
    s[4] = (short)f2b(b.x); s[5] = (short)f2b(b.y);
    s[6] = (short)f2b(b.z); s[7] = (short)f2b(b.w);
    return s;
}

__global__ __launch_bounds__(NT, 1) void lstm2_fused(
    const float* __restrict__ hr,
    const float* __restrict__ glu,
    const float* __restrict__ wih0,
    const float* __restrict__ whh0,
    const float* __restrict__ bih0,
    const float* __restrict__ bhh0,
    const float* __restrict__ wih1,
    const float* __restrict__ whh1,
    const float* __restrict__ bih1,
    const float* __restrict__ bhh1,
    const float* __restrict__ w1,
    const float* __restrict__ b1,
    const float* __restrict__ w2,
    const float* __restrict__ b2,
    float* __restrict__ out)
{
    // h(t) lives in buffer t&1. Rows 8..15 stay zero (MFMA M=16 padding).
    __shared__ __align__(16) unsigned short h0b[2][16][HP];
    __shared__ __align__(16) unsigned short h1b[2][16][HP];
    __shared__ float gbuf[8][4][8][16];   // [wave][gate][row][jj] intra-wave
    __shared__ float hrs[BB][TT + 4];
    __shared__ float glus[BB][TT + 4];
    __shared__ float hid[BB][FFD];

    const int tid  = threadIdx.x;
    const int lane = tid & 63;
    const int wv   = tid >> 6;        // 0..7
    const int nrow = lane & 15;       // MFMA m (A) / n (B) index
    const int kg   = lane >> 4;       // MFMA k-group 0..3
    const int b0   = blockIdx.x * BB;

    // ---- init LDS ----
    {
        unsigned short* p0 = &h0b[0][0][0];
        unsigned short* p1 = &h1b[0][0][0];
        for (int i = tid; i < 2 * 16 * HP; i += NT) { p0[i] = 0; p1[i] = 0; }
        for (int i = tid; i < BB * TT; i += NT) {   // coalesced over t
            int row = i >> 9;
            int t   = i & (TT - 1);
            unsigned gi = (unsigned)(b0 + row) * TT + t;
            hrs[row][t]  = hr[gi];
            glus[row][t] = glu[gi];
        }
    }

    // ---- weight fragments: wave w owns gate cols {128g + 16w + nrow} ----
    // B-frag 16x16x32: lane(n=lane&15, q=lane>>4) holds B[k=32kt+8q+e][n]=W[col][k]
    short8 W0f[4][4];   // [g][kt] whh0, K=128
    short8 W1f[4][8];   // [g][kt] wih1 (kt<4) / whh1 (kt>=4), K=256
#pragma unroll
    for (int g = 0; g < 4; g++) {
        unsigned gc = (unsigned)(128 * g + 16 * wv + nrow);
#pragma unroll
        for (int kt = 0; kt < 4; kt++) {
            unsigned off = gc * HH + kt * 32 + kg * 8;
            W0f[g][kt]     = ldfrag(whh0, off);
            W1f[g][kt]     = ldfrag(wih1, off);
            W1f[g][kt + 4] = ldfrag(whh1, off);
        }
    }
    // pin loop-invariant weights to AGPRs (R8: eliminates scratch spill)
#pragma unroll
    for (int g = 0; g < 4; g++) {
#pragma unroll
        for (int kt = 0; kt < 4; kt++) { asm volatile("" : "+a"(W0f[g][kt])); }
#pragma unroll
        for (int kt = 0; kt < 8; kt++) { asm volatile("" : "+a"(W1f[g][kt])); }
    }

    // ---- per-thread cell units: col j = 16wv+jj; rows rlo and rlo+4 ----
    const int jj  = lane & 15;
    const int rlo = lane >> 4;        // 0..3
    const int j   = 16 * wv + jj;
    float b0c[4], b1c[4], wa[4], wb[4];
#pragma unroll
    for (int g = 0; g < 4; g++) {
        int col = j + 128 * g;
        b0c[g] = bih0[col] + bhh0[col];
        b1c[g] = bih1[col] + bhh1[col];
        wa[g]  = wih0[2 * col];
        wb[g]  = wih0[2 * col + 1];
    }
    float c0[2] = {0.f, 0.f};
    float c1[2] = {0.f, 0.f};
    __syncthreads();

    // ---- recurrence: ONE barrier per iteration ----
    for (int it = 0; it <= TT; it++) {
        const int p = (it + 1) & 1;   // buffer holding h(it-1)
        const int q = it & 1;         // buffer for h0(it); holds h1(it-2)

        // A-frags of h0(it-1) — shared by MM0 and MM1
        short8 a0[4];
#pragma unroll
        for (int kt = 0; kt < 4; kt++)
            a0[kt] = *reinterpret_cast<const short8*>(&h0b[p][nrow][kt * 32 + kg * 8]);

        f32x4 acc[4];
        if (it < TT) {
            // MM0(it): gates0 = h0(it-1) @ whh0^T
#pragma unroll
            for (int g = 0; g < 4; g++) { f32x4 z = {0.f, 0.f, 0.f, 0.f}; acc[g] = z; }
#pragma unroll
            for (int kt = 0; kt < 4; kt++)
#pragma unroll
                for (int g = 0; g < 4; g++)
                    acc[g] = __builtin_amdgcn_mfma_f32_16x16x32_bf16(a0[kt], W0f[g][kt], acc[g], 0, 0, 0);
            // intra-wave handoff (C/D: col=lane&15, row=4*kg+rr)
            if (kg < 2) {
#pragma unroll
                for (int g = 0; g < 4; g++)
#pragma unroll
                    for (int rr = 0; rr < 4; rr++)
                        gbuf[wv][g][4 * kg + rr][nrow] = acc[g][rr];
            }
            // cell0(it): 2 units (rows rlo, rlo+4), all in-register + gbuf reads
#pragma unroll
            for (int rep = 0; rep < 2; rep++) {
                int r = rlo + 4 * rep;
                float xh = hrs[r][it];
                float xg = glus[r][it];
                float pi = gbuf[wv][0][r][jj] + b0c[0] + xh * wa[0] + xg * wb[0];
                float pf = gbuf[wv][1][r][jj] + b0c[1] + xh * wa[1] + xg * wb[1];
                float pg = gbuf[wv][2][r][jj] + b0c[2] + xh * wa[2] + xg * wb[2];
                float po = gbuf[wv][3][r][jj] + b0c[3] + xh * wa[3] + xg * wb[3];
                float ig = sigm(pi), fg = sigm(pf), gg = tanh_f(pg), og = sigm(po);
                float c = fg * c0[rep] + ig * gg;
                c0[rep] = c;
                h0b[q][r][j] = f2b(og * tanh_f(c));   // h0(it) -> buf q
            }
        }
        if (it > 0) {
            // MM1(it-1): gates1 = [h0(it-1), h1(it-2)] @ [wih1; whh1]^T
#pragma unroll
            for (int g = 0; g < 4; g++) { f32x4 z = {0.f, 0.f, 0.f, 0.f}; acc[g] = z; }
#pragma unroll
            for (int kt = 0; kt < 4; kt++)
#pragma unroll
                for (int g = 0; g < 4; g++)
                    acc[g] = __builtin_amdgcn_mfma_f32_16x16x32_bf16(a0[kt], W1f[g][kt], acc[g], 0, 0, 0);
#pragma unroll
            for (int kt = 0; kt < 4; kt++) {
                short8 a1 = *reinterpret_cast<const short8*>(&h1b[q][nrow][kt * 32 + kg * 8]);
#pragma unroll
                for (int g = 0; g < 4; g++)
                    acc[g] = __builtin_amdgcn_mfma_f32_16x16x32_bf16(a1, W1f[g][kt + 4], acc[g], 0, 0, 0);
            }
            if (kg < 2) {
#pragma unroll
                for (int g = 0; g < 4; g++)
#pragma unroll
                    for (int rr = 0; rr < 4; rr++)
                        gbuf[wv][g][4 * kg + rr][nrow] = acc[g][rr];
            }
            // cell1(it-1): h1(it-1) -> buf p
#pragma unroll
            for (int rep = 0; rep < 2; rep++) {
                int r = rlo + 4 * rep;
                float pi = gbuf[wv][0][r][jj] + b1c[0];
                float pf = gbuf[wv][1][r][jj] + b1c[1];
                float pg = gbuf[wv][2][r][jj] + b1c[2];
                float po = gbuf[wv][3][r][jj] + b1c[3];
                float ig = sigm(pi), fg = sigm(pf), gg = tanh_f(pg), og = sigm(po);
                float c = fg * c1[rep] + ig * gg;
                c1[rep] = c;
                h1b[p][r][j] = f2b(og * tanh_f(c));
            }
        }
        __syncthreads();
    }

    // ---- head: h1 final = h1(TT-1) in h1b[(TT-1)&1] = h1b[1] ----
    {
        int r  = tid >> 6;      // 0..7
        int ff = tid & 63;
        float a2 = 0.f;
        for (int k = 0; k < HH; k++)
            a2 += b2f(h1b[1][r][k]) * w1[(unsigned)ff * HH + k];
        hid[r][ff] = fmaxf(a2 + b1[ff], 0.f);
    }
    __syncthreads();
    if (tid < 16) {
        int r = tid >> 1;
        int o = tid & 1;
        float a2 = b2[o];
        for (int k = 0; k < FFD; k++)
            a2 += hid[r][k] * w2[(unsigned)o * FFD + k];
        out[(b0 + r) * 2 + o] = a2;    // fp32 output
    }
}

extern "C" void kernel_launch(void* const* d_in, const int* in_sizes, int n_in,
                              void* d_out, int out_size, void* d_ws, size_t ws_size,
                              hipStream_t stream) {
    const float* hr   = (const float*)d_in[0];
    const float* glu  = (const float*)d_in[1];
    const float* wih0 = (const float*)d_in[2];
    const float* whh0 = (const float*)d_in[3];
    const float* bih0 = (const float*)d_in[4];
    const float* bhh0 = (const float*)d_in[5];
    const float* wih1 = (const float*)d_in[6];
    const float* whh1 = (const float*)d_in[7];
    const float* bih1 = (const float*)d_in[8];
    const float* bhh1 = (const float*)d_in[9];
    const float* w1   = (const float*)d_in[10];
    const float* b1   = (const float*)d_in[11];
    const float* w2   = (const float*)d_in[12];
    const float* b2   = (const float*)d_in[13];
    float* out = (float*)d_out;

    lstm2_fused<<<dim3(2048 / BB), dim3(NT), 0, stream>>>(
        hr, glu, wih0, whh0, bih0, bhh0, wih1, whh1, bih1, bhh1,
        w1, b1, w2, b2, out);
}